// Round 1
// baseline (670.786 us; speedup 1.0000x reference)
//
#include <hip/hip_runtime.h>

#define NN 50000
#define EE 400000
#define CC 128
#define TT 2

typedef float floatx4 __attribute__((ext_vector_type(4)));
typedef short shortx8 __attribute__((ext_vector_type(8)));

__device__ __forceinline__ float bf2f(unsigned u16) { return __uint_as_float(u16 << 16); }
__device__ __forceinline__ unsigned f2bf(float f) {
    unsigned u = __float_as_uint(f);
    return (u + 0x7fffu + ((u >> 16) & 1u)) >> 16;
}
// tanh-approx gelu (jax.nn.gelu default approximate=True), NaN-free form
__device__ __forceinline__ float gelu_f(float x) {
    float u = 0.7978845608028654f * (x + 0.044715f * x * x * x);
    float t = __expf(2.f * u);
    return x * (1.f - 1.f / (t + 1.f));
}

// ---- edge_index dtype probe: int64 arrays have zero high words ----
__global__ void k_detect(const int* __restrict__ ei, int* __restrict__ flag) {
    if (threadIdx.x == 0 && blockIdx.x == 0) {
        int orv = 0;
        for (int i = 1; i < 64; i += 2) orv |= ei[i];
        flag[0] = (orv == 0) ? 1 : 0;
    }
}

__global__ void k_zero(int* __restrict__ p, int n) {
    int i = blockIdx.x * 256 + threadIdx.x;
    if (i < n) p[i] = 0;
}

__global__ void k_count(const int* __restrict__ ei, const int* __restrict__ flag,
                        int* __restrict__ counts) {
    int i = blockIdx.x * 256 + threadIdx.x;
    if (i >= 2 * EE) return;
    int is64 = flag[0];
    int e = i / EE, j = i - e * EE;
    size_t pos = (size_t)(e * 2 + 1) * EE + j;
    int di = is64 ? ei[pos * 2] : ei[pos];
    di = min(max(di, 0), NN - 1);
    atomicAdd(&counts[e * NN + di], 1);
}

#define SCAN_T 1024
#define SCAN_V 4
__global__ void k_scan(const int* __restrict__ counts, int* __restrict__ rowptr,
                       int* __restrict__ cursor) {
    int e = blockIdx.x;
    int tid = threadIdx.x;
    __shared__ int sm[SCAN_T];
    int running = 0;
    const int CH = SCAN_T * SCAN_V;
    for (int base = 0; base < NN; base += CH) {
        int v[SCAN_V];
        int s = 0;
        for (int k2 = 0; k2 < SCAN_V; k2++) {
            int i = base + tid * SCAN_V + k2;
            v[k2] = (i < NN) ? counts[e * NN + i] : 0;
            s += v[k2];
        }
        sm[tid] = s;
        __syncthreads();
        int incl = s;
        for (int off = 1; off < SCAN_T; off <<= 1) {
            int t2 = (tid >= off) ? sm[tid - off] : 0;
            __syncthreads();
            incl += t2;
            sm[tid] = incl;
            __syncthreads();
        }
        int excl = running + incl - s;
        for (int k2 = 0; k2 < SCAN_V; k2++) {
            int i = base + tid * SCAN_V + k2;
            if (i < NN) { rowptr[e * (NN + 1) + i] = excl; cursor[e * NN + i] = excl; }
            excl += v[k2];
        }
        int tot = sm[SCAN_T - 1];
        __syncthreads();
        running += tot;
    }
    if (tid == 0) rowptr[e * (NN + 1) + NN] = running;
}

__global__ void k_scatter(const int* __restrict__ ei, const int* __restrict__ flag,
                          int* __restrict__ cursor, int* __restrict__ csr) {
    int i = blockIdx.x * 256 + threadIdx.x;
    if (i >= 2 * EE) return;
    int is64 = flag[0];
    int e = i / EE, j = i - e * EE;
    size_t ps = (size_t)(e * 2 + 0) * EE + j;
    size_t pd = (size_t)(e * 2 + 1) * EE + j;
    int si = is64 ? ei[ps * 2] : ei[ps];
    int di = is64 ? ei[pd * 2] : ei[pd];
    si = min(max(si, 0), NN - 1);
    di = min(max(di, 0), NN - 1);
    int pos = atomicAdd(&cursor[e * NN + di], 1);
    csr[(size_t)e * EE + pos] = si;
}

__global__ void k_cvt(const float4* __restrict__ x, uint2* __restrict__ xb) {
    int i = blockIdx.x * 256 + threadIdx.x;
    float4 v = x[i];
    uint2 o;
    o.x = f2bf(v.x) | (f2bf(v.y) << 16);
    o.y = f2bf(v.z) | (f2bf(v.w) << 16);
    xb[i] = o;
}

// Build composed weights for layer l:
//  W2[t][kt][n][kk] (bf16, MFMA-B-frag layout), n in [0,384): 0-127 q*p_rel*scale,
//  128-255 Wk∘a_rel[e=t], 256-383 Wv∘m_rel[e=t].  Wa2 likewise for Wa.  beff fp32.
__global__ void k_prep(const float* __restrict__ Wk, const float* __restrict__ Wq,
                       const float* __restrict__ Wv, const float* __restrict__ Wa,
                       const float* __restrict__ bk, const float* __restrict__ bq,
                       const float* __restrict__ bv,
                       const float* __restrict__ a_rel, const float* __restrict__ m_rel,
                       const float* __restrict__ p_rel,
                       unsigned short* __restrict__ W2, unsigned short* __restrict__ Wa2,
                       float* __restrict__ beff, int l) {
    const float SCALE = 0.17677669529663687f;  // 1/sqrt(32)
    int idx = blockIdx.x * 256 + threadIdx.x;
    if (idx < 2 * 384 * 128) {
        int t = idx / (384 * 128);
        int r = idx - t * 384 * 128;
        int n = r >> 7, k = r & 127;
        float val;
        if (n < 128) {
            // q of type t is dest of edge e=1-t
            val = Wq[((l * 2 + t) * 128 + k) * 128 + n] *
                  p_rel[(l * 2 + (1 - t)) * 4 + (n >> 5)] * SCALE;
        } else if (n < 256) {
            int nn = n - 128, h = nn >> 5, f = nn & 31;
            const float* wr = Wk + ((l * 2 + t) * 128 + k) * 128 + h * 32;
            const float* ar = a_rel + (((l * 2 + t) * 4 + h) * 32) * 32 + f;
            float s = 0.f;
            for (int d = 0; d < 32; d++) s += wr[d] * ar[d * 32];
            val = s;
        } else {
            int nn = n - 256, h = nn >> 5, f = nn & 31;
            const float* wr = Wv + ((l * 2 + t) * 128 + k) * 128 + h * 32;
            const float* mr = m_rel + (((l * 2 + t) * 4 + h) * 32) * 32 + f;
            float s = 0.f;
            for (int d = 0; d < 32; d++) s += wr[d] * mr[d * 32];
            val = s;
        }
        W2[(((size_t)t * 4 + (k >> 5)) * 384 + n) * 32 + (k & 31)] = (unsigned short)f2bf(val);
    } else if (idx < 2 * 384 * 128 + 2 * 128 * 128) {
        int r = idx - 2 * 384 * 128;
        int t = r / (128 * 128);
        r -= t * 128 * 128;
        int n = r >> 7, k = r & 127;
        float val = Wa[((l * 2 + t) * 128 + k) * 128 + n];
        Wa2[(((size_t)t * 4 + (k >> 5)) * 128 + n) * 32 + (k & 31)] = (unsigned short)f2bf(val);
    } else if (idx < 2 * 384 * 128 + 2 * 128 * 128 + 2 * 384) {
        int r = idx - (2 * 384 * 128 + 2 * 128 * 128);
        int t = r / 384, n = r - t * 384;
        float val;
        if (n < 128) {
            val = bq[(l * 2 + t) * 128 + n] * p_rel[(l * 2 + (1 - t)) * 4 + (n >> 5)] * SCALE;
        } else if (n < 256) {
            int nn = n - 128, h = nn >> 5, f = nn & 31;
            float s = 0.f;
            for (int d = 0; d < 32; d++)
                s += bk[(l * 2 + t) * 128 + h * 32 + d] *
                     a_rel[(((l * 2 + t) * 4 + h) * 32 + d) * 32 + f];
            val = s;
        } else {
            int nn = n - 256, h = nn >> 5, f = nn & 31;
            float s = 0.f;
            for (int d = 0; d < 32; d++)
                s += bv[(l * 2 + t) * 128 + h * 32 + d] *
                     m_rel[(((l * 2 + t) * 4 + h) * 32 + d) * 32 + f];
            val = s;
        }
        beff[t * 384 + n] = val;
    }
}

// qkv[t][n][384] = x_bf[t] @ W2[t] + beff[t]  (bf16 out)
// block = 4 waves, each wave: 16 rows x 384 cols via 16x16x32 MFMA
__global__ __launch_bounds__(256) void k_gemm_qkv(const unsigned short* __restrict__ xb,
                                                  const unsigned short* __restrict__ W2,
                                                  const float* __restrict__ beff,
                                                  unsigned short* __restrict__ qkv) {
    int t = blockIdx.y;
    int w = threadIdx.x >> 6, lane = threadIdx.x & 63;
    int quad = lane >> 4, ln = lane & 15;
    int row0 = blockIdx.x * 64 + w * 16;
    int arow = min(row0 + ln, NN - 1);
    const unsigned short* xrow = xb + ((size_t)t * NN + arow) * CC;
    shortx8 af[4];
#pragma unroll
    for (int kt = 0; kt < 4; kt++) af[kt] = *(const shortx8*)(xrow + kt * 32 + quad * 8);
    const unsigned short* Wt = W2 + (size_t)t * 4 * 384 * 32;
    floatx4 acc[24];
#pragma unroll
    for (int nt = 0; nt < 24; nt++) acc[nt] = (floatx4){0.f, 0.f, 0.f, 0.f};
#pragma unroll
    for (int nt = 0; nt < 24; nt++) {
        int n = nt * 16 + ln;
#pragma unroll
        for (int kt = 0; kt < 4; kt++) {
            shortx8 bfrag = *(const shortx8*)(Wt + ((size_t)kt * 384 + n) * 32 + quad * 8);
            acc[nt] = __builtin_amdgcn_mfma_f32_16x16x32_bf16(af[kt], bfrag, acc[nt], 0, 0, 0);
        }
    }
#pragma unroll
    for (int nt = 0; nt < 24; nt++) {
        int n = nt * 16 + ln;
        float bias = beff[t * 384 + n];
#pragma unroll
        for (int reg = 0; reg < 4; reg++) {
            int row = row0 + quad * 4 + reg;
            if (row < NN)
                qkv[((size_t)t * NN + row) * 384 + n] = (unsigned short)f2bf(acc[nt][reg] + bias);
        }
    }
}

// Fused dest-centric attention + online softmax + gelu.  One wave per dest node.
// t = dest type (blockIdx.y), e = st = 1-t.  Writes outg[t][n][128] = gelu(agg) bf16.
__global__ __launch_bounds__(256) void k_attn(const unsigned short* __restrict__ qkv,
                                              const int* __restrict__ rowptr,
                                              const int* __restrict__ csr,
                                              unsigned short* __restrict__ outg) {
    int t = blockIdx.y;
    int e = 1 - t;
    int st = 1 - t;
    int w = threadIdx.x >> 6, lane = threadIdx.x & 63;
    int n = blockIdx.x * 4 + w;
    const unsigned short* qrow = qkv + ((size_t)t * NN + n) * 384;
    unsigned qd = *(const unsigned*)(qrow + 2 * lane);
    float q0 = bf2f(qd & 0xffffu), q1 = bf2f(qd >> 16);
    int r0 = rowptr[e * (NN + 1) + n], r1 = rowptr[e * (NN + 1) + n + 1];
    const unsigned short* sbase = qkv + (size_t)st * NN * 384;
    float m = -1e30f, lsum = 0.f, a0 = 0.f, a1 = 0.f;
    for (int j = r0; j < r1; j++) {
        int si = csr[(size_t)e * EE + j];
        const unsigned short* srow = sbase + (size_t)si * 384;
        unsigned kd = *(const unsigned*)(srow + 128 + 2 * lane);
        float p = q0 * bf2f(kd & 0xffffu) + q1 * bf2f(kd >> 16);
        p += __shfl_xor(p, 1, 16);
        p += __shfl_xor(p, 2, 16);
        p += __shfl_xor(p, 4, 16);
        p += __shfl_xor(p, 8, 16);  // att for head = lane>>4 (p_rel*scale folded into q)
        float mnew = fmaxf(m, p);
        float alpha = __expf(m - mnew);
        float wgt = __expf(p - mnew);
        lsum = lsum * alpha + wgt;
        m = mnew;
        unsigned vd = *(const unsigned*)(srow + 256 + 2 * lane);
        a0 = a0 * alpha + wgt * bf2f(vd & 0xffffu);
        a1 = a1 * alpha + wgt * bf2f(vd >> 16);
    }
    float inv = 1.f / (lsum + 1e-16f);
    float v0 = gelu_f(a0 * inv);
    float v1 = gelu_f(a1 * inv);
    *(unsigned*)(outg + ((size_t)t * NN + n) * CC + 2 * lane) =
        f2bf(v0) | (f2bf(v1) << 16);
}

// o = outg @ Wa2 + ba ; x = beta*o + (1-beta)*x ; LayerNorm ; ReLU
__global__ __launch_bounds__(256) void k_epilogue(
    const unsigned short* __restrict__ outg, const unsigned short* __restrict__ Wa2,
    const float* __restrict__ ba, const float* __restrict__ skipv,
    const float* __restrict__ ln_g, const float* __restrict__ ln_b,
    const unsigned short* __restrict__ xb_cur, unsigned short* __restrict__ xb_next,
    float* __restrict__ xout, int l) {
    int t = blockIdx.y;
    int w = threadIdx.x >> 6, lane = threadIdx.x & 63;
    int quad = lane >> 4, ln = lane & 15;
    int row0 = blockIdx.x * 64 + w * 16;
    int arow = min(row0 + ln, NN - 1);
    const unsigned short* grow = outg + ((size_t)t * NN + arow) * CC;
    shortx8 af[4];
#pragma unroll
    for (int kt = 0; kt < 4; kt++) af[kt] = *(const shortx8*)(grow + kt * 32 + quad * 8);
    const unsigned short* Wt = Wa2 + (size_t)t * 4 * CC * 32;
    floatx4 acc[8];
#pragma unroll
    for (int nt = 0; nt < 8; nt++) acc[nt] = (floatx4){0.f, 0.f, 0.f, 0.f};
#pragma unroll
    for (int nt = 0; nt < 8; nt++) {
        int n = nt * 16 + ln;
#pragma unroll
        for (int kt = 0; kt < 4; kt++) {
            shortx8 bfrag = *(const shortx8*)(Wt + ((size_t)kt * CC + n) * 32 + quad * 8);
            acc[nt] = __builtin_amdgcn_mfma_f32_16x16x32_bf16(af[kt], bfrag, acc[nt], 0, 0, 0);
        }
    }
    float sv = skipv[l * TT + t];
    float beta = 1.f / (1.f + __expf(-sv));
    float bias[8], garr[8], barr[8];
#pragma unroll
    for (int nt = 0; nt < 8; nt++) {
        int col = nt * 16 + ln;
        bias[nt] = ba[(l * TT + t) * CC + col];
        garr[nt] = ln_g[(l * TT + t) * CC + col];
        barr[nt] = ln_b[(l * TT + t) * CC + col];
    }
    float xn[8][4];
#pragma unroll
    for (int nt = 0; nt < 8; nt++) {
        int col = nt * 16 + ln;
#pragma unroll
        for (int reg = 0; reg < 4; reg++) {
            int row = min(row0 + quad * 4 + reg, NN - 1);
            float xv = bf2f(xb_cur[((size_t)t * NN + row) * CC + col]);
            float o = acc[nt][reg] + bias[nt];
            xn[nt][reg] = beta * o + (1.f - beta) * xv;
        }
    }
    float s1[4] = {0, 0, 0, 0}, s2[4] = {0, 0, 0, 0};
#pragma unroll
    for (int nt = 0; nt < 8; nt++)
#pragma unroll
        for (int reg = 0; reg < 4; reg++) {
            float v = xn[nt][reg];
            s1[reg] += v;
            s2[reg] += v * v;
        }
#pragma unroll
    for (int reg = 0; reg < 4; reg++) {
#pragma unroll
        for (int o = 1; o < 16; o <<= 1) {
            s1[reg] += __shfl_xor(s1[reg], o, 16);
            s2[reg] += __shfl_xor(s2[reg], o, 16);
        }
    }
    float mu[4], rs[4];
#pragma unroll
    for (int reg = 0; reg < 4; reg++) {
        mu[reg] = s1[reg] * (1.f / CC);
        float var = s2[reg] * (1.f / CC) - mu[reg] * mu[reg];
        rs[reg] = rsqrtf(var + 1e-5f);
    }
#pragma unroll
    for (int nt = 0; nt < 8; nt++) {
        int col = nt * 16 + ln;
#pragma unroll
        for (int reg = 0; reg < 4; reg++) {
            int row = row0 + quad * 4 + reg;
            if (row < NN) {
                float y = (xn[nt][reg] - mu[reg]) * rs[reg] * garr[nt] + barr[nt];
                y = fmaxf(y, 0.f);
                if (xout)
                    xout[(size_t)row * CC + col] = y;
                else
                    xb_next[((size_t)t * NN + row) * CC + col] = (unsigned short)f2bf(y);
            }
        }
    }
}

extern "C" void kernel_launch(void* const* d_in, const int* in_sizes, int n_in,
                              void* d_out, int out_size, void* d_ws, size_t ws_size,
                              hipStream_t stream) {
    const float* x = (const float*)d_in[0];
    const int* ei = (const int*)d_in[1];
    const float* Wk = (const float*)d_in[2];
    const float* bk = (const float*)d_in[3];
    const float* Wq = (const float*)d_in[4];
    const float* bq = (const float*)d_in[5];
    const float* Wv = (const float*)d_in[6];
    const float* bv = (const float*)d_in[7];
    const float* Wa = (const float*)d_in[8];
    const float* ba = (const float*)d_in[9];
    const float* skip = (const float*)d_in[10];
    const float* a_rel = (const float*)d_in[11];
    const float* m_rel = (const float*)d_in[12];
    const float* p_rel = (const float*)d_in[13];
    const float* ln_g = (const float*)d_in[14];
    const float* ln_b = (const float*)d_in[15];

    char* ws = (char*)d_ws;
    size_t off = 0;
    auto alloc = [&](size_t b) {
        size_t o = off;
        off = (off + b + 255) & ~(size_t)255;
        return o;
    };
    unsigned short* xbA = (unsigned short*)(ws + alloc((size_t)TT * NN * CC * 2));
    unsigned short* xbB = (unsigned short*)(ws + alloc((size_t)TT * NN * CC * 2));
    unsigned short* qkv = (unsigned short*)(ws + alloc((size_t)TT * NN * 384 * 2));
    unsigned short* outg = (unsigned short*)(ws + alloc((size_t)TT * NN * CC * 2));
    unsigned short* W2 = (unsigned short*)(ws + alloc((size_t)TT * 4 * 384 * 32 * 2));
    unsigned short* Wa2 = (unsigned short*)(ws + alloc((size_t)TT * 4 * CC * 32 * 2));
    float* beff = (float*)(ws + alloc((size_t)TT * 384 * 4));
    int* counts = (int*)(ws + alloc((size_t)2 * NN * 4));
    int* cursor = (int*)(ws + alloc((size_t)2 * NN * 4));
    int* rowptr = (int*)(ws + alloc((size_t)2 * (NN + 1) * 4));
    int* csr = (int*)(ws + alloc((size_t)2 * EE * 4));
    int* flag = (int*)(ws + alloc(256));
    (void)ws_size; (void)in_sizes; (void)n_in; (void)out_size;

    k_detect<<<1, 64, 0, stream>>>(ei, flag);
    k_zero<<<(2 * NN + 255) / 256, 256, 0, stream>>>(counts, 2 * NN);
    k_count<<<(2 * EE + 255) / 256, 256, 0, stream>>>(ei, flag, counts);
    k_scan<<<2, SCAN_T, 0, stream>>>(counts, rowptr, cursor);
    k_scatter<<<(2 * EE + 255) / 256, 256, 0, stream>>>(ei, flag, cursor, csr);
    k_cvt<<<(TT * NN * CC / 4 + 255) / 256, 256, 0, stream>>>((const float4*)x, (uint2*)xbA);

    for (int l = 0; l < 2; l++) {
        const unsigned short* xb_cur = (l == 0) ? xbA : xbB;
        k_prep<<<(2 * 384 * 128 + 2 * 128 * 128 + 2 * 384 + 255) / 256, 256, 0, stream>>>(
            Wk, Wq, Wv, Wa, bk, bq, bv, a_rel, m_rel, p_rel, W2, Wa2, beff, l);
        k_gemm_qkv<<<dim3(782, 2), 256, 0, stream>>>(xb_cur, W2, beff, qkv);
        int nty = (l == 0) ? 2 : 1;  // layer 2: only type-0 output needed
        k_attn<<<dim3(NN / 4, nty), 256, 0, stream>>>(qkv, rowptr, csr, outg);
        k_epilogue<<<dim3(782, nty), 256, 0, stream>>>(
            outg, Wa2, ba, skip, ln_g, ln_b, xb_cur, xbB,
            (l == 1) ? (float*)d_out : nullptr, l);
    }
}

// Round 2
// 527.142 us; speedup vs baseline: 1.2725x; 1.2725x over previous
//
#include <hip/hip_runtime.h>

#define NN 50000
#define EE 400000
#define CC 128
#define TT 2

typedef float floatx4 __attribute__((ext_vector_type(4)));
typedef short shortx8 __attribute__((ext_vector_type(8)));

__device__ __forceinline__ float bf2f(unsigned u16) { return __uint_as_float(u16 << 16); }
__device__ __forceinline__ unsigned f2bf(float f) {
    unsigned u = __float_as_uint(f);
    return (u + 0x7fffu + ((u >> 16) & 1u)) >> 16;
}
// tanh-approx gelu (jax.nn.gelu default approximate=True), NaN-free form
__device__ __forceinline__ float gelu_f(float x) {
    float u = 0.7978845608028654f * (x + 0.044715f * x * x * x);
    float t = __expf(2.f * u);
    return x * (1.f - 1.f / (t + 1.f));
}

// ---- edge_index dtype probe: int64 arrays have zero high words ----
__global__ void k_detect(const int* __restrict__ ei, int* __restrict__ flag) {
    if (threadIdx.x == 0 && blockIdx.x == 0) {
        int orv = 0;
        for (int i = 1; i < 64; i += 2) orv |= ei[i];
        flag[0] = (orv == 0) ? 1 : 0;
    }
}

__global__ void k_count(const int* __restrict__ ei, const int* __restrict__ flag,
                        int* __restrict__ counts) {
    int i = blockIdx.x * 256 + threadIdx.x;
    if (i >= 2 * EE) return;
    int is64 = flag[0];
    int e = i / EE, j = i - e * EE;
    size_t pos = (size_t)(e * 2 + 1) * EE + j;
    int di = is64 ? ei[pos * 2] : ei[pos];
    di = min(max(di, 0), NN - 1);
    atomicAdd(&counts[e * NN + di], 1);
}

// shfl-based scan: 1024 threads (16 waves), 4 elems/thread, 2 barriers/chunk
#define SCAN_T 1024
#define SCAN_V 4
__global__ __launch_bounds__(1024) void k_scan(const int* __restrict__ counts,
                                               int* __restrict__ rowptr,
                                               int* __restrict__ cursor) {
    int e = blockIdx.x;
    int tid = threadIdx.x;
    int lane = tid & 63, wid = tid >> 6;
    __shared__ int wsum[16];
    __shared__ int ctot;
    int running = 0;
    const int CH = SCAN_T * SCAN_V;
    for (int base = 0; base < NN; base += CH) {
        int v[SCAN_V];
        int s = 0;
#pragma unroll
        for (int k2 = 0; k2 < SCAN_V; k2++) {
            int i = base + tid * SCAN_V + k2;
            v[k2] = (i < NN) ? counts[e * NN + i] : 0;
            s += v[k2];
        }
        // wave-level inclusive scan of s
        int incl = s;
#pragma unroll
        for (int off = 1; off < 64; off <<= 1) {
            int tt = __shfl_up(incl, off);
            if (lane >= off) incl += tt;
        }
        if (lane == 63) wsum[wid] = incl;
        __syncthreads();
        if (wid == 0 && lane < 16) {
            int ws = wsum[lane];
            int wincl = ws;
#pragma unroll
            for (int off = 1; off < 16; off <<= 1) {
                int tt = __shfl_up(wincl, off, 16);
                if ((lane & 15) >= off) wincl += tt;
            }
            wsum[lane] = wincl - ws;  // exclusive prefix of wave sums
            if (lane == 15) ctot = wincl;
        }
        __syncthreads();
        int excl = running + wsum[wid] + (incl - s);
#pragma unroll
        for (int k2 = 0; k2 < SCAN_V; k2++) {
            int i = base + tid * SCAN_V + k2;
            if (i < NN) { rowptr[e * (NN + 1) + i] = excl; cursor[e * NN + i] = excl; }
            excl += v[k2];
        }
        running += ctot;
        __syncthreads();
    }
    if (tid == 0) rowptr[e * (NN + 1) + NN] = running;
}

__global__ void k_scatter(const int* __restrict__ ei, const int* __restrict__ flag,
                          int* __restrict__ cursor, int* __restrict__ csr) {
    int i = blockIdx.x * 256 + threadIdx.x;
    if (i >= 2 * EE) return;
    int is64 = flag[0];
    int e = i / EE, j = i - e * EE;
    size_t ps = (size_t)(e * 2 + 0) * EE + j;
    size_t pd = (size_t)(e * 2 + 1) * EE + j;
    int si = is64 ? ei[ps * 2] : ei[ps];
    int di = is64 ? ei[pd * 2] : ei[pd];
    si = min(max(si, 0), NN - 1);
    di = min(max(di, 0), NN - 1);
    int pos = atomicAdd(&cursor[e * NN + di], 1);
    csr[(size_t)e * EE + pos] = si;
}

__global__ void k_cvt(const float4* __restrict__ x, uint2* __restrict__ xb) {
    int i = blockIdx.x * 256 + threadIdx.x;
    float4 v = x[i];
    uint2 o;
    o.x = f2bf(v.x) | (f2bf(v.y) << 16);
    o.y = f2bf(v.z) | (f2bf(v.w) << 16);
    xb[i] = o;
}

// Composed weights, both layers at once (l = blockIdx.y):
//  W2[l][t][kt][n][kk] bf16 B-frag layout; n in [0,384): q*p_rel*scale | Wk∘a_rel | Wv∘m_rel
__global__ void k_prep(const float* __restrict__ Wk, const float* __restrict__ Wq,
                       const float* __restrict__ Wv, const float* __restrict__ Wa,
                       const float* __restrict__ bk, const float* __restrict__ bq,
                       const float* __restrict__ bv,
                       const float* __restrict__ a_rel, const float* __restrict__ m_rel,
                       const float* __restrict__ p_rel,
                       unsigned short* __restrict__ W2, unsigned short* __restrict__ Wa2,
                       float* __restrict__ beff) {
    const float SCALE = 0.17677669529663687f;  // 1/sqrt(32)
    int l = blockIdx.y;
    int idx = blockIdx.x * 256 + threadIdx.x;
    if (idx < 2 * 384 * 128) {
        int t = idx / (384 * 128);
        int r = idx - t * 384 * 128;
        int n = r >> 7, k = r & 127;
        float val;
        if (n < 128) {
            val = Wq[((l * 2 + t) * 128 + k) * 128 + n] *
                  p_rel[(l * 2 + (1 - t)) * 4 + (n >> 5)] * SCALE;
        } else if (n < 256) {
            int nn = n - 128, h = nn >> 5, f = nn & 31;
            const float* wr = Wk + ((l * 2 + t) * 128 + k) * 128 + h * 32;
            const float* ar = a_rel + (((l * 2 + t) * 4 + h) * 32) * 32 + f;
            float s = 0.f;
            for (int d = 0; d < 32; d++) s += wr[d] * ar[d * 32];
            val = s;
        } else {
            int nn = n - 256, h = nn >> 5, f = nn & 31;
            const float* wr = Wv + ((l * 2 + t) * 128 + k) * 128 + h * 32;
            const float* mr = m_rel + (((l * 2 + t) * 4 + h) * 32) * 32 + f;
            float s = 0.f;
            for (int d = 0; d < 32; d++) s += wr[d] * mr[d * 32];
            val = s;
        }
        W2[(((size_t)(l * 2 + t) * 4 + (k >> 5)) * 384 + n) * 32 + (k & 31)] =
            (unsigned short)f2bf(val);
    } else if (idx < 2 * 384 * 128 + 2 * 128 * 128) {
        int r = idx - 2 * 384 * 128;
        int t = r / (128 * 128);
        r -= t * 128 * 128;
        int n = r >> 7, k = r & 127;
        float val = Wa[((l * 2 + t) * 128 + k) * 128 + n];
        Wa2[(((size_t)(l * 2 + t) * 4 + (k >> 5)) * 128 + n) * 32 + (k & 31)] =
            (unsigned short)f2bf(val);
    } else if (idx < 2 * 384 * 128 + 2 * 128 * 128 + 2 * 384) {
        int r = idx - (2 * 384 * 128 + 2 * 128 * 128);
        int t = r / 384, n = r - t * 384;
        float val;
        if (n < 128) {
            val = bq[(l * 2 + t) * 128 + n] * p_rel[(l * 2 + (1 - t)) * 4 + (n >> 5)] * SCALE;
        } else if (n < 256) {
            int nn = n - 128, h = nn >> 5, f = nn & 31;
            float s = 0.f;
            for (int d = 0; d < 32; d++)
                s += bk[(l * 2 + t) * 128 + h * 32 + d] *
                     a_rel[(((l * 2 + t) * 4 + h) * 32 + d) * 32 + f];
            val = s;
        } else {
            int nn = n - 256, h = nn >> 5, f = nn & 31;
            float s = 0.f;
            for (int d = 0; d < 32; d++)
                s += bv[(l * 2 + t) * 128 + h * 32 + d] *
                     m_rel[(((l * 2 + t) * 4 + h) * 32 + d) * 32 + f];
            val = s;
        }
        beff[(l * 2 + t) * 384 + n] = val;
    }
}

// qkv[t][n][384] = x_bf[t] @ W2[l][t] + beff.  Wave: 32 rows x 96 cols,
// B-frags loaded once per (nt,kt), reused across 2 row-sets.
__global__ __launch_bounds__(256) void k_gemm_qkv(const unsigned short* __restrict__ xb,
                                                  const unsigned short* __restrict__ W2,
                                                  const float* __restrict__ beff,
                                                  unsigned short* __restrict__ qkv, int l) {
    int t = blockIdx.y;
    int wid = threadIdx.x >> 6, lane = threadIdx.x & 63;
    int quad = lane >> 4, ln = lane & 15;
    int row_base = blockIdx.x * 32;
    const unsigned short* Wt = W2 + (size_t)(l * 2 + t) * 4 * 384 * 32;
    shortx8 af[2][4];
#pragma unroll
    for (int rs = 0; rs < 2; rs++) {
        int arow = min(row_base + rs * 16 + ln, NN - 1);
        const unsigned short* xrow = xb + ((size_t)t * NN + arow) * CC;
#pragma unroll
        for (int kt = 0; kt < 4; kt++) af[rs][kt] = *(const shortx8*)(xrow + kt * 32 + quad * 8);
    }
    floatx4 acc[6][2];
#pragma unroll
    for (int nt = 0; nt < 6; nt++)
#pragma unroll
        for (int rs = 0; rs < 2; rs++) acc[nt][rs] = (floatx4){0.f, 0.f, 0.f, 0.f};
#pragma unroll
    for (int nt = 0; nt < 6; nt++) {
        int n = wid * 96 + nt * 16 + ln;
#pragma unroll
        for (int kt = 0; kt < 4; kt++) {
            shortx8 bfrag = *(const shortx8*)(Wt + ((size_t)kt * 384 + n) * 32 + quad * 8);
            acc[nt][0] = __builtin_amdgcn_mfma_f32_16x16x32_bf16(af[0][kt], bfrag, acc[nt][0], 0, 0, 0);
            acc[nt][1] = __builtin_amdgcn_mfma_f32_16x16x32_bf16(af[1][kt], bfrag, acc[nt][1], 0, 0, 0);
        }
    }
#pragma unroll
    for (int nt = 0; nt < 6; nt++) {
        int n = wid * 96 + nt * 16 + ln;
        float bias = beff[(l * 2 + t) * 384 + n];
#pragma unroll
        for (int rs = 0; rs < 2; rs++)
#pragma unroll
            for (int reg = 0; reg < 4; reg++) {
                int row = row_base + rs * 16 + quad * 4 + reg;
                if (row < NN)
                    qkv[((size_t)t * NN + row) * 384 + n] =
                        (unsigned short)f2bf(acc[nt][rs][reg] + bias);
            }
    }
}

// Dest-centric attention.  Wave = 1 dest node; 64 lanes = 4 edge slots x 16 segs.
// Lane (e4, s): loads dwordx4 = 8 bf16 elems [s*8, s*8+8) of k,v row of edge e4.
// Head of seg s = s>>2 (32 elems = 4 segs).  No online max (|logit| small).
__global__ __launch_bounds__(256) void k_attn(const unsigned short* __restrict__ qkv,
                                              const int* __restrict__ rowptr,
                                              const int* __restrict__ csr,
                                              unsigned short* __restrict__ outg) {
    int t = blockIdx.y;
    int e = 1 - t;
    int st = 1 - t;
    int wid = threadIdx.x >> 6, lane = threadIdx.x & 63;
    int n = blockIdx.x * 4 + wid;
    int e4 = lane >> 4, s = lane & 15;
    const unsigned short* qrow = qkv + ((size_t)t * NN + n) * 384;
    uint4 qd = *(const uint4*)(qrow + s * 8);
    float qf[8];
    qf[0] = bf2f(qd.x & 0xffffu); qf[1] = bf2f(qd.x >> 16);
    qf[2] = bf2f(qd.y & 0xffffu); qf[3] = bf2f(qd.y >> 16);
    qf[4] = bf2f(qd.z & 0xffffu); qf[5] = bf2f(qd.z >> 16);
    qf[6] = bf2f(qd.w & 0xffffu); qf[7] = bf2f(qd.w >> 16);
    int r0 = rowptr[e * (NN + 1) + n], r1 = rowptr[e * (NN + 1) + n + 1];
    r0 = __builtin_amdgcn_readfirstlane(r0);
    r1 = __builtin_amdgcn_readfirstlane(r1);
    const int* csrp = csr + (size_t)e * EE;
    const unsigned short* sbase = qkv + (size_t)st * NN * 384;
    float acc[8] = {0.f, 0.f, 0.f, 0.f, 0.f, 0.f, 0.f, 0.f};
    float lsum = 0.f;

    auto load_chunk = [&](int jj, uint4& kd, uint4& vd, float& msk) {
        int idx = min(jj + e4, r1 - 1);
        int si = csrp[idx];
        const unsigned short* row = sbase + (size_t)si * 384;
        kd = *(const uint4*)(row + 128 + s * 8);
        vd = *(const uint4*)(row + 256 + s * 8);
        msk = (jj + e4 < r1) ? 1.f : 0.f;
    };
    auto process = [&](const uint4& kd, const uint4& vd, float msk) {
        float p = 0.f;
        p = fmaf(qf[0], bf2f(kd.x & 0xffffu), p); p = fmaf(qf[1], bf2f(kd.x >> 16), p);
        p = fmaf(qf[2], bf2f(kd.y & 0xffffu), p); p = fmaf(qf[3], bf2f(kd.y >> 16), p);
        p = fmaf(qf[4], bf2f(kd.z & 0xffffu), p); p = fmaf(qf[5], bf2f(kd.z >> 16), p);
        p = fmaf(qf[6], bf2f(kd.w & 0xffffu), p); p = fmaf(qf[7], bf2f(kd.w >> 16), p);
        p += __shfl_xor(p, 1);
        p += __shfl_xor(p, 2);  // 4 segs of one head now all hold full dot
        float w = __expf(p) * msk;
        lsum += w;
        acc[0] = fmaf(w, bf2f(vd.x & 0xffffu), acc[0]);
        acc[1] = fmaf(w, bf2f(vd.x >> 16), acc[1]);
        acc[2] = fmaf(w, bf2f(vd.y & 0xffffu), acc[2]);
        acc[3] = fmaf(w, bf2f(vd.y >> 16), acc[3]);
        acc[4] = fmaf(w, bf2f(vd.z & 0xffffu), acc[4]);
        acc[5] = fmaf(w, bf2f(vd.z >> 16), acc[5]);
        acc[6] = fmaf(w, bf2f(vd.w & 0xffffu), acc[6]);
        acc[7] = fmaf(w, bf2f(vd.w >> 16), acc[7]);
    };

    if (r0 < r1) {
        uint4 kdA, vdA;
        float mA;
        load_chunk(r0, kdA, vdA, mA);
        int j = r0;
        for (; j + 4 < r1; j += 4) {
            uint4 kdB, vdB;
            float mB;
            load_chunk(j + 4, kdB, vdB, mB);  // prefetch next chunk
            process(kdA, vdA, mA);
            kdA = kdB; vdA = vdB; mA = mB;
        }
        process(kdA, vdA, mA);
    }
    // reduce across the 4 edge slots
#pragma unroll
    for (int i = 0; i < 8; i++) {
        acc[i] += __shfl_xor(acc[i], 16);
        acc[i] += __shfl_xor(acc[i], 32);
    }
    lsum += __shfl_xor(lsum, 16);
    lsum += __shfl_xor(lsum, 32);
    float inv = 1.f / (lsum + 1e-16f);
    if (e4 == 0) {
        uint4 o;
        float g0, g1;
        g0 = gelu_f(acc[0] * inv); g1 = gelu_f(acc[1] * inv); o.x = f2bf(g0) | (f2bf(g1) << 16);
        g0 = gelu_f(acc[2] * inv); g1 = gelu_f(acc[3] * inv); o.y = f2bf(g0) | (f2bf(g1) << 16);
        g0 = gelu_f(acc[4] * inv); g1 = gelu_f(acc[5] * inv); o.z = f2bf(g0) | (f2bf(g1) << 16);
        g0 = gelu_f(acc[6] * inv); g1 = gelu_f(acc[7] * inv); o.w = f2bf(g0) | (f2bf(g1) << 16);
        *(uint4*)(outg + ((size_t)t * NN + n) * CC + s * 8) = o;
    }
}

// o = outg @ Wa2 + ba ; x = beta*o + (1-beta)*x ; LayerNorm ; ReLU
__global__ __launch_bounds__(256) void k_epilogue(
    const unsigned short* __restrict__ outg, const unsigned short* __restrict__ Wa2,
    const float* __restrict__ ba, const float* __restrict__ skipv,
    const float* __restrict__ ln_g, const float* __restrict__ ln_b,
    const unsigned short* __restrict__ xb_cur, unsigned short* __restrict__ xb_next,
    float* __restrict__ xout, int l) {
    int t = blockIdx.y;
    int w = threadIdx.x >> 6, lane = threadIdx.x & 63;
    int quad = lane >> 4, ln = lane & 15;
    int row0 = blockIdx.x * 64 + w * 16;
    int arow = min(row0 + ln, NN - 1);
    const unsigned short* grow = outg + ((size_t)t * NN + arow) * CC;
    shortx8 af[4];
#pragma unroll
    for (int kt = 0; kt < 4; kt++) af[kt] = *(const shortx8*)(grow + kt * 32 + quad * 8);
    const unsigned short* Wt = Wa2 + (size_t)(l * 2 + t) * 4 * CC * 32;
    floatx4 acc[8];
#pragma unroll
    for (int nt = 0; nt < 8; nt++) acc[nt] = (floatx4){0.f, 0.f, 0.f, 0.f};
#pragma unroll
    for (int nt = 0; nt < 8; nt++) {
        int n = nt * 16 + ln;
#pragma unroll
        for (int kt = 0; kt < 4; kt++) {
            shortx8 bfrag = *(const shortx8*)(Wt + ((size_t)kt * CC + n) * 32 + quad * 8);
            acc[nt] = __builtin_amdgcn_mfma_f32_16x16x32_bf16(af[kt], bfrag, acc[nt], 0, 0, 0);
        }
    }
    float sv = skipv[l * TT + t];
    float beta = 1.f / (1.f + __expf(-sv));
    float bias[8], garr[8], barr[8];
#pragma unroll
    for (int nt = 0; nt < 8; nt++) {
        int col = nt * 16 + ln;
        bias[nt] = ba[(l * TT + t) * CC + col];
        garr[nt] = ln_g[(l * TT + t) * CC + col];
        barr[nt] = ln_b[(l * TT + t) * CC + col];
    }
    float xn[8][4];
#pragma unroll
    for (int nt = 0; nt < 8; nt++) {
        int col = nt * 16 + ln;
#pragma unroll
        for (int reg = 0; reg < 4; reg++) {
            int row = min(row0 + quad * 4 + reg, NN - 1);
            float xv = bf2f(xb_cur[((size_t)t * NN + row) * CC + col]);
            float o = acc[nt][reg] + bias[nt];
            xn[nt][reg] = beta * o + (1.f - beta) * xv;
        }
    }
    float s1[4] = {0, 0, 0, 0}, s2[4] = {0, 0, 0, 0};
#pragma unroll
    for (int nt = 0; nt < 8; nt++)
#pragma unroll
        for (int reg = 0; reg < 4; reg++) {
            float v = xn[nt][reg];
            s1[reg] += v;
            s2[reg] += v * v;
        }
#pragma unroll
    for (int reg = 0; reg < 4; reg++) {
#pragma unroll
        for (int o = 1; o < 16; o <<= 1) {
            s1[reg] += __shfl_xor(s1[reg], o, 16);
            s2[reg] += __shfl_xor(s2[reg], o, 16);
        }
    }
    float mu[4], rs[4];
#pragma unroll
    for (int reg = 0; reg < 4; reg++) {
        mu[reg] = s1[reg] * (1.f / CC);
        float var = s2[reg] * (1.f / CC) - mu[reg] * mu[reg];
        rs[reg] = rsqrtf(var + 1e-5f);
    }
#pragma unroll
    for (int nt = 0; nt < 8; nt++) {
        int col = nt * 16 + ln;
#pragma unroll
        for (int reg = 0; reg < 4; reg++) {
            int row = row0 + quad * 4 + reg;
            if (row < NN) {
                float y = (xn[nt][reg] - mu[reg]) * rs[reg] * garr[nt] + barr[nt];
                y = fmaxf(y, 0.f);
                if (xout)
                    xout[(size_t)row * CC + col] = y;
                else
                    xb_next[((size_t)t * NN + row) * CC + col] = (unsigned short)f2bf(y);
            }
        }
    }
}

extern "C" void kernel_launch(void* const* d_in, const int* in_sizes, int n_in,
                              void* d_out, int out_size, void* d_ws, size_t ws_size,
                              hipStream_t stream) {
    const float* x = (const float*)d_in[0];
    const int* ei = (const int*)d_in[1];
    const float* Wk = (const float*)d_in[2];
    const float* bk = (const float*)d_in[3];
    const float* Wq = (const float*)d_in[4];
    const float* bq = (const float*)d_in[5];
    const float* Wv = (const float*)d_in[6];
    const float* bv = (const float*)d_in[7];
    const float* Wa = (const float*)d_in[8];
    const float* ba = (const float*)d_in[9];
    const float* skip = (const float*)d_in[10];
    const float* a_rel = (const float*)d_in[11];
    const float* m_rel = (const float*)d_in[12];
    const float* p_rel = (const float*)d_in[13];
    const float* ln_g = (const float*)d_in[14];
    const float* ln_b = (const float*)d_in[15];

    char* ws = (char*)d_ws;
    size_t off = 0;
    auto alloc = [&](size_t b) {
        size_t o = off;
        off = (off + b + 255) & ~(size_t)255;
        return o;
    };
    unsigned short* xbA = (unsigned short*)(ws + alloc((size_t)TT * NN * CC * 2));
    unsigned short* xbB = (unsigned short*)(ws + alloc((size_t)TT * NN * CC * 2));
    unsigned short* qkv = (unsigned short*)(ws + alloc((size_t)TT * NN * 384 * 2));
    unsigned short* outg = (unsigned short*)(ws + alloc((size_t)TT * NN * CC * 2));
    unsigned short* W2 = (unsigned short*)(ws + alloc((size_t)2 * TT * 4 * 384 * 32 * 2));
    unsigned short* Wa2 = (unsigned short*)(ws + alloc((size_t)2 * TT * 4 * CC * 32 * 2));
    float* beff = (float*)(ws + alloc((size_t)2 * TT * 384 * 4));
    int* counts = (int*)(ws + alloc((size_t)2 * NN * 4));
    int* cursor = (int*)(ws + alloc((size_t)2 * NN * 4));
    int* rowptr = (int*)(ws + alloc((size_t)2 * (NN + 1) * 4));
    int* csr = (int*)(ws + alloc((size_t)2 * EE * 4));
    int* flag = (int*)(ws + alloc(256));
    (void)ws_size; (void)in_sizes; (void)n_in; (void)out_size;

    k_detect<<<1, 64, 0, stream>>>(ei, flag);
    hipMemsetAsync(counts, 0, (size_t)2 * NN * 4, stream);
    k_count<<<(2 * EE + 255) / 256, 256, 0, stream>>>(ei, flag, counts);
    k_scan<<<2, SCAN_T, 0, stream>>>(counts, rowptr, cursor);
    k_scatter<<<(2 * EE + 255) / 256, 256, 0, stream>>>(ei, flag, cursor, csr);
    k_cvt<<<(TT * NN * CC / 4 + 255) / 256, 256, 0, stream>>>((const float4*)x, (uint2*)xbA);
    k_prep<<<dim3((2 * 384 * 128 + 2 * 128 * 128 + 2 * 384 + 255) / 256, 2), 256, 0, stream>>>(
        Wk, Wq, Wv, Wa, bk, bq, bv, a_rel, m_rel, p_rel, W2, Wa2, beff);

    for (int l = 0; l < 2; l++) {
        const unsigned short* xb_cur = (l == 0) ? xbA : xbB;
        k_gemm_qkv<<<dim3((NN + 31) / 32, 2), 256, 0, stream>>>(xb_cur, W2, beff, qkv, l);
        int nty = (l == 0) ? 2 : 1;  // layer 2: only type-0 output needed
        k_attn<<<dim3(NN / 4, nty), 256, 0, stream>>>(qkv, rowptr, csr, outg);
        k_epilogue<<<dim3((NN + 63) / 64, nty), 256, 0, stream>>>(
            outg, Wa2, ba, skip, ln_g, ln_b, xb_cur, xbB,
            (l == 1) ? (float*)d_out : nullptr, l);
    }
}

// Round 4
// 469.577 us; speedup vs baseline: 1.4285x; 1.1226x over previous
//
#include <hip/hip_runtime.h>

#define NN 50000
#define EE 400000
#define CC 128
#define TT 2

typedef float floatx4 __attribute__((ext_vector_type(4)));
typedef _Float16 half8 __attribute__((ext_vector_type(8)));
typedef _Float16 half2t __attribute__((ext_vector_type(2)));

__device__ __forceinline__ unsigned pk2h(float a, float b) {
    return __builtin_bit_cast(unsigned, __builtin_amdgcn_cvt_pkrtz(a, b));
}
// tanh-approx gelu (jax.nn.gelu default approximate=True), NaN-free form
__device__ __forceinline__ float gelu_f(float x) {
    float u = 0.7978845608028654f * (x + 0.044715f * x * x * x);
    float t = __expf(2.f * u);
    return x * (1.f - 1.f / (t + 1.f));
}
// f16x2 dot product accumulating f32: v_dot2_f32_f16 when available
__device__ __forceinline__ float dot2h(unsigned a, unsigned b, float c) {
#if __has_builtin(__builtin_amdgcn_fdot2)
    return __builtin_amdgcn_fdot2(__builtin_bit_cast(half2t, a),
                                  __builtin_bit_cast(half2t, b), c, false);
#else
    half2t av = __builtin_bit_cast(half2t, a), bv = __builtin_bit_cast(half2t, b);
    c = fmaf((float)av.x, (float)bv.x, c);
    return fmaf((float)av.y, (float)bv.y, c);
#endif
}

// ---- edge_index dtype probe: int64 arrays have zero high words ----
__global__ void k_detect(const int* __restrict__ ei, int* __restrict__ flag) {
    if (threadIdx.x == 0 && blockIdx.x == 0) {
        int orv = 0;
        for (int i = 1; i < 64; i += 2) orv |= ei[i];
        flag[0] = (orv == 0) ? 1 : 0;
    }
}

__global__ void k_count(const int* __restrict__ ei, const int* __restrict__ flag,
                        int* __restrict__ counts) {
    int i = blockIdx.x * 256 + threadIdx.x;
    if (i >= 2 * EE) return;
    int is64 = flag[0];
    int e = i / EE, j = i - e * EE;
    size_t pos = (size_t)(e * 2 + 1) * EE + j;
    int di = is64 ? ei[pos * 2] : ei[pos];
    di = min(max(di, 0), NN - 1);
    atomicAdd(&counts[e * NN + di], 1);
}

// ---- 3-phase scan: 49 blocks x 1024 elems per edge type ----
#define SCB ((NN + 1023) / 1024)
__global__ __launch_bounds__(256) void k_scan1(const int* __restrict__ counts,
                                               int* __restrict__ rowptr,
                                               int* __restrict__ bsum) {
    int e = blockIdx.y, b = blockIdx.x;
    int tid = threadIdx.x, lane = tid & 63, wid = tid >> 6;
    __shared__ int wsum[4];
    int base = b * 1024 + tid * 4;
    int v[4], s = 0;
#pragma unroll
    for (int k2 = 0; k2 < 4; k2++) {
        int i = base + k2;
        v[k2] = (i < NN) ? counts[e * NN + i] : 0;
        s += v[k2];
    }
    int incl = s;
#pragma unroll
    for (int off = 1; off < 64; off <<= 1) {
        int t2 = __shfl_up(incl, off);
        if (lane >= off) incl += t2;
    }
    if (lane == 63) wsum[wid] = incl;
    __syncthreads();
    int woff = 0;
    for (int w2 = 0; w2 < wid; w2++) woff += wsum[w2];
    int excl = woff + incl - s;
#pragma unroll
    for (int k2 = 0; k2 < 4; k2++) {
        int i = base + k2;
        if (i < NN) rowptr[e * (NN + 1) + i] = excl;
        excl += v[k2];
    }
    if (tid == 255) bsum[e * SCB + b] = woff + incl;
}

__global__ void k_scan2(int* __restrict__ bsum, int* __restrict__ rowptr) {
    int e = threadIdx.x >> 6, lane = threadIdx.x & 63;
    int v = (lane < SCB) ? bsum[e * SCB + lane] : 0;
    int incl = v;
#pragma unroll
    for (int off = 1; off < 64; off <<= 1) {
        int t2 = __shfl_up(incl, off);
        if (lane >= off) incl += t2;
    }
    if (lane < SCB) bsum[e * SCB + lane] = incl - v;
    if (lane == 63) rowptr[e * (NN + 1) + NN] = incl;
}

__global__ __launch_bounds__(256) void k_scan3(int* __restrict__ rowptr,
                                               const int* __restrict__ bsum,
                                               int* __restrict__ cursor) {
    int e = blockIdx.y, b = blockIdx.x;
    int off = bsum[e * SCB + b];
    int base = b * 1024 + threadIdx.x * 4;
#pragma unroll
    for (int k2 = 0; k2 < 4; k2++) {
        int i = base + k2;
        if (i < NN) {
            int r = rowptr[e * (NN + 1) + i] + off;
            rowptr[e * (NN + 1) + i] = r;
            cursor[e * NN + i] = r;
        }
    }
}

__global__ void k_scatter(const int* __restrict__ ei, const int* __restrict__ flag,
                          int* __restrict__ cursor, int* __restrict__ csr) {
    int i = blockIdx.x * 256 + threadIdx.x;
    if (i >= 2 * EE) return;
    int is64 = flag[0];
    int e = i / EE, j = i - e * EE;
    size_t ps = (size_t)(e * 2 + 0) * EE + j;
    size_t pd = (size_t)(e * 2 + 1) * EE + j;
    int si = is64 ? ei[ps * 2] : ei[ps];
    int di = is64 ? ei[pd * 2] : ei[pd];
    si = min(max(si, 0), NN - 1);
    di = min(max(di, 0), NN - 1);
    int pos = atomicAdd(&cursor[e * NN + di], 1);
    csr[(size_t)e * EE + pos] = si;
}

__global__ void k_cvt(const float4* __restrict__ x, uint2* __restrict__ xb) {
    int i = blockIdx.x * 256 + threadIdx.x;
    float4 v = x[i];
    uint2 o;
    o.x = pk2h(v.x, v.y);
    o.y = pk2h(v.z, v.w);
    xb[i] = o;
}

// Composed weights, both layers (l = blockIdx.y), f16 B-frag layout:
//  W2[l][t][kt][n][kk]; n in [0,384): q*p_rel*scale | Wk∘a_rel | Wv∘m_rel
__global__ void k_prep(const float* __restrict__ Wk, const float* __restrict__ Wq,
                       const float* __restrict__ Wv, const float* __restrict__ Wa,
                       const float* __restrict__ bk, const float* __restrict__ bq,
                       const float* __restrict__ bv,
                       const float* __restrict__ a_rel, const float* __restrict__ m_rel,
                       const float* __restrict__ p_rel,
                       _Float16* __restrict__ W2, _Float16* __restrict__ Wa2,
                       float* __restrict__ beff) {
    const float SCALE = 0.17677669529663687f;  // 1/sqrt(32)
    int l = blockIdx.y;
    int idx = blockIdx.x * 256 + threadIdx.x;
    if (idx < 2 * 384 * 128) {
        int t = idx / (384 * 128);
        int r = idx - t * 384 * 128;
        int n = r >> 7, k = r & 127;
        float val;
        if (n < 128) {
            val = Wq[((l * 2 + t) * 128 + k) * 128 + n] *
                  p_rel[(l * 2 + (1 - t)) * 4 + (n >> 5)] * SCALE;
        } else if (n < 256) {
            int nn = n - 128, h = nn >> 5, f = nn & 31;
            const float* wr = Wk + ((l * 2 + t) * 128 + k) * 128 + h * 32;
            const float* ar = a_rel + (((l * 2 + t) * 4 + h) * 32) * 32 + f;
            float s = 0.f;
            for (int d = 0; d < 32; d++) s += wr[d] * ar[d * 32];
            val = s;
        } else {
            int nn = n - 256, h = nn >> 5, f = nn & 31;
            const float* wr = Wv + ((l * 2 + t) * 128 + k) * 128 + h * 32;
            const float* mr = m_rel + (((l * 2 + t) * 4 + h) * 32) * 32 + f;
            float s = 0.f;
            for (int d = 0; d < 32; d++) s += wr[d] * mr[d * 32];
            val = s;
        }
        W2[(((size_t)(l * 2 + t) * 4 + (k >> 5)) * 384 + n) * 32 + (k & 31)] = (_Float16)val;
    } else if (idx < 2 * 384 * 128 + 2 * 128 * 128) {
        int r = idx - 2 * 384 * 128;
        int t = r / (128 * 128);
        r -= t * 128 * 128;
        int n = r >> 7, k = r & 127;
        float val = Wa[((l * 2 + t) * 128 + k) * 128 + n];
        Wa2[(((size_t)(l * 2 + t) * 4 + (k >> 5)) * 128 + n) * 32 + (k & 31)] = (_Float16)val;
    } else if (idx < 2 * 384 * 128 + 2 * 128 * 128 + 2 * 384) {
        int r = idx - (2 * 384 * 128 + 2 * 128 * 128);
        int t = r / 384, n = r - t * 384;
        float val;
        if (n < 128) {
            val = bq[(l * 2 + t) * 128 + n] * p_rel[(l * 2 + (1 - t)) * 4 + (n >> 5)] * SCALE;
        } else if (n < 256) {
            int nn = n - 128, h = nn >> 5, f = nn & 31;
            float s = 0.f;
            for (int d = 0; d < 32; d++)
                s += bk[(l * 2 + t) * 128 + h * 32 + d] *
                     a_rel[(((l * 2 + t) * 4 + h) * 32 + d) * 32 + f];
            val = s;
        } else {
            int nn = n - 256, h = nn >> 5, f = nn & 31;
            float s = 0.f;
            for (int d = 0; d < 32; d++)
                s += bv[(l * 2 + t) * 128 + h * 32 + d] *
                     m_rel[(((l * 2 + t) * 4 + h) * 32 + d) * 32 + f];
            val = s;
        }
        beff[(l * 2 + t) * 384 + n] = val;
    }
}

// qkv[t][n][col0..col0+NT*64) = x[t] @ W2[l][t] + beff.  Wave: 32 rows x NT*16 cols.
template <int NT>
__global__ __launch_bounds__(256) void k_gemm_qkv(const _Float16* __restrict__ xb,
                                                  const _Float16* __restrict__ W2,
                                                  const float* __restrict__ beff,
                                                  _Float16* __restrict__ qkv, int l,
                                                  int t0, int col0) {
    int t = t0 + blockIdx.y;
    int wid = threadIdx.x >> 6, lane = threadIdx.x & 63;
    int quad = lane >> 4, ln = lane & 15;
    int row_base = blockIdx.x * 32;
    const _Float16* Wt = W2 + (size_t)(l * 2 + t) * 4 * 384 * 32;
    half8 af[2][4];
#pragma unroll
    for (int rs = 0; rs < 2; rs++) {
        int arow = min(row_base + rs * 16 + ln, NN - 1);
        const _Float16* xrow = xb + ((size_t)t * NN + arow) * CC;
#pragma unroll
        for (int kt = 0; kt < 4; kt++) af[rs][kt] = *(const half8*)(xrow + kt * 32 + quad * 8);
    }
    floatx4 acc[NT][2];
#pragma unroll
    for (int nt = 0; nt < NT; nt++)
#pragma unroll
        for (int rs = 0; rs < 2; rs++) acc[nt][rs] = (floatx4){0.f, 0.f, 0.f, 0.f};
#pragma unroll
    for (int nt = 0; nt < NT; nt++) {
        int n = col0 + wid * NT * 16 + nt * 16 + ln;
#pragma unroll
        for (int kt = 0; kt < 4; kt++) {
            half8 bfrag = *(const half8*)(Wt + ((size_t)kt * 384 + n) * 32 + quad * 8);
            acc[nt][0] = __builtin_amdgcn_mfma_f32_16x16x32_f16(af[0][kt], bfrag, acc[nt][0], 0, 0, 0);
            acc[nt][1] = __builtin_amdgcn_mfma_f32_16x16x32_f16(af[1][kt], bfrag, acc[nt][1], 0, 0, 0);
        }
    }
#pragma unroll
    for (int nt = 0; nt < NT; nt++) {
        int n = col0 + wid * NT * 16 + nt * 16 + ln;
        float bias = beff[(l * 2 + t) * 384 + n];
#pragma unroll
        for (int rs = 0; rs < 2; rs++)
#pragma unroll
            for (int reg = 0; reg < 4; reg++) {
                int row = row_base + rs * 16 + quad * 4 + reg;
                if (row < NN)
                    qkv[((size_t)t * NN + row) * 384 + n] = (_Float16)(acc[nt][rs][reg] + bias);
            }
    }
}

// Dest-centric attention.  Wave = 1 dest node; 64 lanes = 4 edge slots x 16 segs.
// f16 tables: q.k via v_dot2_f32_f16 (packed, no unpack); v-agg scalar fma.
// Writes RAW aggregate (gelu deferred to epilogue).
__global__ __launch_bounds__(256) void k_attn(const _Float16* __restrict__ qkv,
                                              const int* __restrict__ rowptr,
                                              const int* __restrict__ csr,
                                              _Float16* __restrict__ outg) {
    int t = blockIdx.y;
    int e = 1 - t;
    int st = 1 - t;
    int wid = threadIdx.x >> 6, lane = threadIdx.x & 63;
    int n = blockIdx.x * 4 + wid;
    int e4 = lane >> 4, s = lane & 15;
    const _Float16* qrow = qkv + ((size_t)t * NN + n) * 384;
    uint4 qd = *(const uint4*)(qrow + s * 8);
    int r0 = rowptr[e * (NN + 1) + n], r1 = rowptr[e * (NN + 1) + n + 1];
    r0 = __builtin_amdgcn_readfirstlane(r0);
    r1 = __builtin_amdgcn_readfirstlane(r1);
    const int* csrp = csr + (size_t)e * EE;
    const _Float16* sbase = qkv + (size_t)st * NN * 384;
    float acc[8] = {0.f, 0.f, 0.f, 0.f, 0.f, 0.f, 0.f, 0.f};
    float lsum = 0.f;

    auto load_chunk = [&](int jj, uint4& kd, uint4& vd, float& msk) {
        int idx = min(jj + e4, r1 - 1);
        int si = csrp[idx];
        const _Float16* row = sbase + (size_t)si * 384;
        kd = *(const uint4*)(row + 128 + s * 8);
        vd = *(const uint4*)(row + 256 + s * 8);
        msk = (jj + e4 < r1) ? 1.f : 0.f;
    };
    auto process = [&](const uint4& kd, const uint4& vd, float msk) {
        float p = 0.f;
        p = dot2h(kd.x, qd.x, p);
        p = dot2h(kd.y, qd.y, p);
        p = dot2h(kd.z, qd.z, p);
        p = dot2h(kd.w, qd.w, p);
        p += __shfl_xor(p, 1);
        p += __shfl_xor(p, 2);  // 4 segs of one head now hold the full head dot
        float w = __expf(p) * msk;
        lsum += w;
        half2t v0 = __builtin_bit_cast(half2t, vd.x), v1 = __builtin_bit_cast(half2t, vd.y);
        half2t v2 = __builtin_bit_cast(half2t, vd.z), v3 = __builtin_bit_cast(half2t, vd.w);
        acc[0] = fmaf(w, (float)v0.x, acc[0]);
        acc[1] = fmaf(w, (float)v0.y, acc[1]);
        acc[2] = fmaf(w, (float)v1.x, acc[2]);
        acc[3] = fmaf(w, (float)v1.y, acc[3]);
        acc[4] = fmaf(w, (float)v2.x, acc[4]);
        acc[5] = fmaf(w, (float)v2.y, acc[5]);
        acc[6] = fmaf(w, (float)v3.x, acc[6]);
        acc[7] = fmaf(w, (float)v3.y, acc[7]);
    };

    if (r0 < r1) {
        uint4 kdA, vdA;
        float mA;
        load_chunk(r0, kdA, vdA, mA);
        int j = r0;
        for (; j + 4 < r1; j += 4) {
            uint4 kdB, vdB;
            float mB;
            load_chunk(j + 4, kdB, vdB, mB);  // prefetch next chunk
            process(kdA, vdA, mA);
            kdA = kdB; vdA = vdB; mA = mB;
        }
        process(kdA, vdA, mA);
    }
#pragma unroll
    for (int i = 0; i < 8; i++) {
        acc[i] += __shfl_xor(acc[i], 16);
        acc[i] += __shfl_xor(acc[i], 32);
    }
    lsum += __shfl_xor(lsum, 16);
    lsum += __shfl_xor(lsum, 32);
    float inv = 1.f / (lsum + 1e-16f);
    if (e4 == 0) {
        uint4 o;
        o.x = pk2h(acc[0] * inv, acc[1] * inv);
        o.y = pk2h(acc[2] * inv, acc[3] * inv);
        o.z = pk2h(acc[4] * inv, acc[5] * inv);
        o.w = pk2h(acc[6] * inv, acc[7] * inv);
        *(uint4*)(outg + ((size_t)t * NN + n) * CC + s * 8) = o;
    }
}

// o = gelu(outg) @ Wa2 + ba ; x = beta*o + (1-beta)*x ; LayerNorm ; ReLU
__global__ __launch_bounds__(256) void k_epilogue(
    const _Float16* __restrict__ outg, const _Float16* __restrict__ Wa2,
    const float* __restrict__ ba, const float* __restrict__ skipv,
    const float* __restrict__ ln_g, const float* __restrict__ ln_b,
    const _Float16* __restrict__ xb_cur, _Float16* __restrict__ xb_next,
    float* __restrict__ xout, int l) {
    int t = blockIdx.y;
    int w = threadIdx.x >> 6, lane = threadIdx.x & 63;
    int quad = lane >> 4, ln = lane & 15;
    int row0 = blockIdx.x * 64 + w * 16;
    int arow = min(row0 + ln, NN - 1);
    const _Float16* grow = outg + ((size_t)t * NN + arow) * CC;
    half8 af[4];
#pragma unroll
    for (int kt = 0; kt < 4; kt++) {
        uint4 gd = *(const uint4*)(grow + kt * 32 + quad * 8);
        half2t h0 = __builtin_bit_cast(half2t, gd.x), h1 = __builtin_bit_cast(half2t, gd.y);
        half2t h2 = __builtin_bit_cast(half2t, gd.z), h3 = __builtin_bit_cast(half2t, gd.w);
        uint4 pk;
        pk.x = pk2h(gelu_f((float)h0.x), gelu_f((float)h0.y));
        pk.y = pk2h(gelu_f((float)h1.x), gelu_f((float)h1.y));
        pk.z = pk2h(gelu_f((float)h2.x), gelu_f((float)h2.y));
        pk.w = pk2h(gelu_f((float)h3.x), gelu_f((float)h3.y));
        af[kt] = __builtin_bit_cast(half8, pk);
    }
    const _Float16* Wt = Wa2 + (size_t)(l * 2 + t) * 4 * CC * 32;
    floatx4 acc[8];
#pragma unroll
    for (int nt = 0; nt < 8; nt++) acc[nt] = (floatx4){0.f, 0.f, 0.f, 0.f};
#pragma unroll
    for (int nt = 0; nt < 8; nt++) {
        int n = nt * 16 + ln;
#pragma unroll
        for (int kt = 0; kt < 4; kt++) {
            half8 bfrag = *(const half8*)(Wt + ((size_t)kt * CC + n) * 32 + quad * 8);
            acc[nt] = __builtin_amdgcn_mfma_f32_16x16x32_f16(af[kt], bfrag, acc[nt], 0, 0, 0);
        }
    }
    float sv = skipv[l * TT + t];
    float beta = 1.f / (1.f + __expf(-sv));
    float bias[8], garr[8], barr[8];
#pragma unroll
    for (int nt = 0; nt < 8; nt++) {
        int col = nt * 16 + ln;
        bias[nt] = ba[(l * TT + t) * CC + col];
        garr[nt] = ln_g[(l * TT + t) * CC + col];
        barr[nt] = ln_b[(l * TT + t) * CC + col];
    }
    float xn[8][4];
#pragma unroll
    for (int nt = 0; nt < 8; nt++) {
        int col = nt * 16 + ln;
#pragma unroll
        for (int reg = 0; reg < 4; reg++) {
            int row = min(row0 + quad * 4 + reg, NN - 1);
            float xv = (float)xb_cur[((size_t)t * NN + row) * CC + col];
            float o = acc[nt][reg] + bias[nt];
            xn[nt][reg] = beta * o + (1.f - beta) * xv;
        }
    }
    float s1[4] = {0, 0, 0, 0}, s2[4] = {0, 0, 0, 0};
#pragma unroll
    for (int nt = 0; nt < 8; nt++)
#pragma unroll
        for (int reg = 0; reg < 4; reg++) {
            float v = xn[nt][reg];
            s1[reg] += v;
            s2[reg] += v * v;
        }
#pragma unroll
    for (int reg = 0; reg < 4; reg++) {
#pragma unroll
        for (int o = 1; o < 16; o <<= 1) {
            s1[reg] += __shfl_xor(s1[reg], o, 16);
            s2[reg] += __shfl_xor(s2[reg], o, 16);
        }
    }
    float mu[4], rs[4];
#pragma unroll
    for (int reg = 0; reg < 4; reg++) {
        mu[reg] = s1[reg] * (1.f / CC);
        float var = s2[reg] * (1.f / CC) - mu[reg] * mu[reg];
        rs[reg] = rsqrtf(var + 1e-5f);
    }
#pragma unroll
    for (int nt = 0; nt < 8; nt++) {
        int col = nt * 16 + ln;
#pragma unroll
        for (int reg = 0; reg < 4; reg++) {
            int row = row0 + quad * 4 + reg;
            if (row < NN) {
                float y = (xn[nt][reg] - mu[reg]) * rs[reg] * garr[nt] + barr[nt];
                y = fmaxf(y, 0.f);
                if (xout)
                    xout[(size_t)row * CC + col] = y;
                else
                    xb_next[((size_t)t * NN + row) * CC + col] = (_Float16)y;
            }
        }
    }
}

extern "C" void kernel_launch(void* const* d_in, const int* in_sizes, int n_in,
                              void* d_out, int out_size, void* d_ws, size_t ws_size,
                              hipStream_t stream) {
    const float* x = (const float*)d_in[0];
    const int* ei = (const int*)d_in[1];
    const float* Wk = (const float*)d_in[2];
    const float* bk = (const float*)d_in[3];
    const float* Wq = (const float*)d_in[4];
    const float* bq = (const float*)d_in[5];
    const float* Wv = (const float*)d_in[6];
    const float* bv = (const float*)d_in[7];
    const float* Wa = (const float*)d_in[8];
    const float* ba = (const float*)d_in[9];
    const float* skip = (const float*)d_in[10];
    const float* a_rel = (const float*)d_in[11];
    const float* m_rel = (const float*)d_in[12];
    const float* p_rel = (const float*)d_in[13];
    const float* ln_g = (const float*)d_in[14];
    const float* ln_b = (const float*)d_in[15];

    char* ws = (char*)d_ws;
    size_t off = 0;
    auto alloc = [&](size_t b) {
        size_t o = off;
        off = (off + b + 255) & ~(size_t)255;
        return o;
    };
    _Float16* xbA = (_Float16*)(ws + alloc((size_t)TT * NN * CC * 2));
    _Float16* xbB = (_Float16*)(ws + alloc((size_t)TT * NN * CC * 2));
    _Float16* qkv = (_Float16*)(ws + alloc((size_t)TT * NN * 384 * 2));
    _Float16* outg = (_Float16*)(ws + alloc((size_t)TT * NN * CC * 2));
    _Float16* W2 = (_Float16*)(ws + alloc((size_t)2 * TT * 4 * 384 * 32 * 2));
    _Float16* Wa2 = (_Float16*)(ws + alloc((size_t)2 * TT * 4 * CC * 32 * 2));
    float* beff = (float*)(ws + alloc((size_t)2 * TT * 384 * 4));
    int* counts = (int*)(ws + alloc((size_t)2 * NN * 4));
    int* cursor = (int*)(ws + alloc((size_t)2 * NN * 4));
    int* rowptr = (int*)(ws + alloc((size_t)2 * (NN + 1) * 4));
    int* csr = (int*)(ws + alloc((size_t)2 * EE * 4));
    int* flag = (int*)(ws + alloc(256));
    int* bsum = (int*)(ws + alloc((size_t)2 * SCB * 4 + 256));
    (void)ws_size; (void)in_sizes; (void)n_in; (void)out_size;

    k_detect<<<1, 64, 0, stream>>>(ei, flag);
    (void)hipMemsetAsync(counts, 0, (size_t)2 * NN * 4, stream);
    k_count<<<(2 * EE + 255) / 256, 256, 0, stream>>>(ei, flag, counts);
    k_scan1<<<dim3(SCB, 2), 256, 0, stream>>>(counts, rowptr, bsum);
    k_scan2<<<1, 128, 0, stream>>>(bsum, rowptr);
    k_scan3<<<dim3(SCB, 2), 256, 0, stream>>>(rowptr, bsum, cursor);
    k_scatter<<<(2 * EE + 255) / 256, 256, 0, stream>>>(ei, flag, cursor, csr);
    k_cvt<<<(TT * NN * CC / 4 + 255) / 256, 256, 0, stream>>>((const float4*)x, (uint2*)xbA);
    k_prep<<<dim3((2 * 384 * 128 + 2 * 128 * 128 + 2 * 384 + 255) / 256, 2), 256, 0, stream>>>(
        Wk, Wq, Wv, Wa, bk, bq, bv, a_rel, m_rel, p_rel, W2, Wa2, beff);

    const int GB = (NN + 31) / 32;
    // layer 0: full qkv for both types
    k_gemm_qkv<6><<<dim3(GB, 2), 256, 0, stream>>>(xbA, W2, beff, qkv, 0, 0, 0);
    k_attn<<<dim3(NN / 4, 2), 256, 0, stream>>>(qkv, rowptr, csr, outg);
    k_epilogue<<<dim3((NN + 63) / 64, 2), 256, 0, stream>>>(
        outg, Wa2, ba, skip, ln_g, ln_b, xbA, xbB, nullptr, 0);
    // layer 1: only t0 output needed -> t0 needs q cols [0,128), t1 needs k/v cols [128,384)
    k_gemm_qkv<2><<<dim3(GB, 1), 256, 0, stream>>>(xbB, W2, beff, qkv, 1, 0, 0);
    k_gemm_qkv<4><<<dim3(GB, 1), 256, 0, stream>>>(xbB, W2, beff, qkv, 1, 1, 128);
    k_attn<<<dim3(NN / 4, 1), 256, 0, stream>>>(qkv, rowptr, csr, outg);
    k_epilogue<<<dim3((NN + 63) / 64, 1), 256, 0, stream>>>(
        outg, Wa2, ba, skip, ln_g, ln_b, xbB, nullptr, (float*)d_out, 1);
}